// Round 2
// baseline (286.725 us; speedup 1.0000x reference)
//
#include <hip/hip_runtime.h>

#define BLOCK 256
#define WPB 4                    // waves (rows) per block
#define C_DIM 10000
#define C4 (C_DIM / 4)           // 2500 float4s per row
#define NIT4 ((C4 + 63) / 64)    // 40 iterations per wave
#define TAU 1.0f
#define CAP 512                  // per-wave candidate capacity (mean ~228 at PIV_HI, +19 sigma)
#define PIV_HI 2.0f
#define PIV_LO 1.0f

// Monotone bijection float -> uint32 (larger float => larger key)
__device__ __forceinline__ unsigned flip_key(float f) {
    unsigned u = __float_as_uint(f);
    return (u & 0x80000000u) ? ~u : (u | 0x80000000u);
}
__device__ __forceinline__ float unflip_key(unsigned k) {
    unsigned u = (k & 0x80000000u) ? (k & 0x7fffffffu) : ~k;
    return __uint_as_float(u);
}
// # of set bits in m strictly below my lane (64-lane)
__device__ __forceinline__ int mbcnt64(unsigned long long m) {
    return (int)__builtin_amdgcn_mbcnt_hi((unsigned)(m >> 32),
               __builtin_amdgcn_mbcnt_lo((unsigned)(m & 0xffffffffu), 0u));
}

__global__ void zero_out_kernel(float* out, int n) {
    int i = blockIdx.x * blockDim.x + threadIdx.x;
    if (i < n) out[i] = 0.f;
}

// Wave-uniform radix bin pick: each lane owns 4 bins (hv), suffix-scan across
// the wave, exactly one lane picks; result broadcast via shuffles. No LDS, no barrier.
__device__ __forceinline__ void wave_pick(uint4 hv, int lane, int shift,
                                          unsigned& prefix, unsigned& kr, unsigned& cnt) {
    unsigned loc = hv.x + hv.y + hv.z + hv.w;
    unsigned suf = loc;
    #pragma unroll
    for (int off = 1; off < 64; off <<= 1) {
        unsigned o = (unsigned)__shfl_down((int)suf, off);
        if (lane + off < 64) suf += o;
    }
    unsigned sufex = suf - loc;              // candidates in bins strictly above my 4
    unsigned s3 = sufex + hv.w;
    unsigned s2 = s3 + hv.z;
    unsigned s1 = s2 + hv.y;
    unsigned s0 = s1 + hv.x;
    int bsel = -1; unsigned nkr = 0u, ncnt = 0u;
    if      (s3 >= kr && s3 - hv.w < kr) { bsel = 4 * lane + 3; nkr = kr - (s3 - hv.w); ncnt = hv.w; }
    else if (s2 >= kr && s2 - hv.z < kr) { bsel = 4 * lane + 2; nkr = kr - (s2 - hv.z); ncnt = hv.z; }
    else if (s1 >= kr && s1 - hv.y < kr) { bsel = 4 * lane + 1; nkr = kr - (s1 - hv.y); ncnt = hv.y; }
    else if (s0 >= kr && s0 - hv.x < kr) { bsel = 4 * lane + 0; nkr = kr - (s0 - hv.x); ncnt = hv.x; }
    unsigned long long pm = __ballot(bsel >= 0);
    int src = __ffsll((unsigned long long)pm) - 1;   // exactly one lane picked
    prefix |= ((unsigned)__shfl(bsel, src)) << shift;
    kr  = (unsigned)__shfl((int)nkr, src);
    cnt = (unsigned)__shfl((int)ncnt, src);
}

// One wave per row. Entirely wave-synchronous: no __syncthreads anywhere.
__global__ __launch_bounds__(BLOCK, 4) void topk_la_loss_kernel(
    const float* __restrict__ logit, const int* __restrict__ target,
    const float* __restrict__ lcn, const int* __restrict__ kpc,
    float* __restrict__ out, int B) {
    __shared__ unsigned candk[WPB][CAP];         // per-wave private segments
    __shared__ unsigned short candi[WPB][CAP];
    __shared__ unsigned hist[WPB][256];

    const int tid = threadIdx.x;
    const int lane = tid & 63;
    const int wid = tid >> 6;
    const int row = blockIdx.x * WPB + wid;
    if (row >= B) return;                        // safe: no barriers in kernel

    const float* lrow = logit + (size_t)row * C_DIM;
    unsigned* ck = candk[wid];
    unsigned short* ci = candi[wid];
    unsigned* h = hist[wid];

    const int t = target[row];                   // uniform loads (broadcast)
    int k = kpc[t]; if (k > C_DIM) k = C_DIM;

    // ---- Fused sweep: z = sum exp(adj) (no max-sub; |madj|>80 guard), max(adj),
    //      ballot-compact logit >= PIV_HI into this wave's LDS segment.
    float z = 0.f, madj = -__builtin_inff();
    unsigned nb = 0u;                            // wave-uniform running count
    #pragma unroll 2
    for (int it = 0; it < NIT4; ++it) {
        const int j4 = it * 64 + lane;
        float4 f, l;
        if (j4 < C4) {
            f = ((const float4*)lrow)[j4];
            l = ((const float4*)lcn)[j4];
        } else {                                 // uniform trip count for ballots
            f = make_float4(-1e30f, -1e30f, -1e30f, -1e30f);
            l = make_float4(0.f, 0.f, 0.f, 0.f);
        }
        const float a0 = f.x + TAU * l.x, a1 = f.y + TAU * l.y;
        const float a2 = f.z + TAU * l.z, a3 = f.w + TAU * l.w;
        z += __expf(a0) + __expf(a1) + __expf(a2) + __expf(a3);   // exp(-1e30)=0
        madj = fmaxf(madj, fmaxf(fmaxf(a0, a1), fmaxf(a2, a3)));
        const int j = 4 * j4;
        unsigned long long m;
        m = __ballot(f.x >= PIV_HI);
        if (f.x >= PIV_HI) { unsigned p = nb + (unsigned)mbcnt64(m); if (p < CAP) { ck[p] = __float_as_uint(f.x); ci[p] = (unsigned short)(j + 0); } }
        nb += (unsigned)__popcll(m);
        m = __ballot(f.y >= PIV_HI);
        if (f.y >= PIV_HI) { unsigned p = nb + (unsigned)mbcnt64(m); if (p < CAP) { ck[p] = __float_as_uint(f.y); ci[p] = (unsigned short)(j + 1); } }
        nb += (unsigned)__popcll(m);
        m = __ballot(f.z >= PIV_HI);
        if (f.z >= PIV_HI) { unsigned p = nb + (unsigned)mbcnt64(m); if (p < CAP) { ck[p] = __float_as_uint(f.z); ci[p] = (unsigned short)(j + 2); } }
        nb += (unsigned)__popcll(m);
        m = __ballot(f.w >= PIV_HI);
        if (f.w >= PIV_HI) { unsigned p = nb + (unsigned)mbcnt64(m); if (p < CAP) { ck[p] = __float_as_uint(f.w); ci[p] = (unsigned short)(j + 3); } }
        nb += (unsigned)__popcll(m);
    }
    #pragma unroll
    for (int off = 32; off; off >>= 1) madj = fmaxf(madj, __shfl_xor(madj, off));

    unsigned n = nb;                             // already wave-uniform
    int path = (n >= (unsigned)k && n <= CAP) ? 0 : ((n < (unsigned)k) ? 1 : 2);

    // ---- Rare: too few candidates at PIV_HI -> recompact at PIV_LO
    if (path == 1) {
        nb = 0u;
        for (int it = 0; it < NIT4; ++it) {
            const int j4 = it * 64 + lane;
            float4 f;
            if (j4 < C4) f = ((const float4*)lrow)[j4];
            else f = make_float4(-1e30f, -1e30f, -1e30f, -1e30f);
            const int j = 4 * j4;
            unsigned long long m;
            m = __ballot(f.x >= PIV_LO);
            if (f.x >= PIV_LO) { unsigned p = nb + (unsigned)mbcnt64(m); if (p < CAP) { ck[p] = __float_as_uint(f.x); ci[p] = (unsigned short)(j + 0); } }
            nb += (unsigned)__popcll(m);
            m = __ballot(f.y >= PIV_LO);
            if (f.y >= PIV_LO) { unsigned p = nb + (unsigned)mbcnt64(m); if (p < CAP) { ck[p] = __float_as_uint(f.y); ci[p] = (unsigned short)(j + 1); } }
            nb += (unsigned)__popcll(m);
            m = __ballot(f.z >= PIV_LO);
            if (f.z >= PIV_LO) { unsigned p = nb + (unsigned)mbcnt64(m); if (p < CAP) { ck[p] = __float_as_uint(f.z); ci[p] = (unsigned short)(j + 2); } }
            nb += (unsigned)__popcll(m);
            m = __ballot(f.w >= PIV_LO);
            if (f.w >= PIV_LO) { unsigned p = nb + (unsigned)mbcnt64(m); if (p < CAP) { ck[p] = __float_as_uint(f.w); ci[p] = (unsigned short)(j + 3); } }
            nb += (unsigned)__popcll(m);
        }
        n = nb;
        path = (n >= (unsigned)k && n <= CAP) ? 0 : 2;
    }

    float thresh;
    if (path == 0) {
        // ---- Exact byte-radix select among n LDS candidates (all >= PIV > 0 ->
        //      raw float bits order like uints). cnt==1 early exit. Wave-local.
        const int nc = (int)n;
        unsigned prefix = 0u, kr = (unsigned)k, cnt = n, kmask = 0u;
        for (int q = 0; q < 4; ++q) {
            if (cnt == 1u) break;                // wave-uniform
            const int shift = 24 - 8 * q;
            *(uint4*)&h[4 * lane] = make_uint4(0u, 0u, 0u, 0u);
            for (int i = lane; i < nc; i += 64) {
                unsigned kk = ck[i];
                if ((kk & kmask) == prefix) atomicAdd(&h[(kk >> shift) & 0xFFu], 1u);
            }
            uint4 hv = *(const uint4*)&h[4 * lane];
            wave_pick(hv, lane, shift, prefix, kr, cnt);
            kmask |= (0xFFu << shift);
        }
        if (cnt == 1u && kmask != 0xFFFFFFFFu) { // unique survivor: fetch full bits
            unsigned found = 0u;
            for (int i = lane; i < nc; i += 64) {
                unsigned kk = ck[i];
                if ((kk & kmask) == prefix) found = kk;   // exactly one match wave-wide
            }
            #pragma unroll
            for (int off = 32; off; off >>= 1) found |= (unsigned)__shfl_xor((int)found, off);
            prefix = found;
        }
        thresh = __uint_as_float(prefix);
    } else {
        // ---- Generic fallback (never hot): full-row radix on flipped keys, per-wave
        unsigned prefix = 0u, kr = (unsigned)k, cnt = 0u;
        for (int p = 0; p < 4; ++p) {
            const int shift = 24 - 8 * p;
            const unsigned pmask = p ? (0xFFFFFFFFu << (shift + 8)) : 0u;
            *(uint4*)&h[4 * lane] = make_uint4(0u, 0u, 0u, 0u);
            for (int it = 0; it < NIT4; ++it) {
                const int j4 = it * 64 + lane;
                if (j4 < C4) {
                    float4 f = ((const float4*)lrow)[j4];
                    unsigned kk;
                    kk = flip_key(f.x); if ((kk & pmask) == prefix) atomicAdd(&h[(kk >> shift) & 0xFFu], 1u);
                    kk = flip_key(f.y); if ((kk & pmask) == prefix) atomicAdd(&h[(kk >> shift) & 0xFFu], 1u);
                    kk = flip_key(f.z); if ((kk & pmask) == prefix) atomicAdd(&h[(kk >> shift) & 0xFFu], 1u);
                    kk = flip_key(f.w); if ((kk & pmask) == prefix) atomicAdd(&h[(kk >> shift) & 0xFFu], 1u);
                }
            }
            uint4 hv = *(const uint4*)&h[4 * lane];
            wave_pick(hv, lane, shift, prefix, kr, cnt);
        }
        thresh = unflip_key(prefix);
    }

    const bool rare = fabsf(madj) > 80.f;        // exp(adj) over/underflow guard
    float sm = 0.f;
    if (!rare) {
        if (path == 0) {
            // masked set is a subset of the candidates
            const int nc = (int)n;
            for (int i = lane; i < nc; i += 64) {
                const float v = __uint_as_float(ck[i]);
                if (v >= thresh) sm += __expf(v + TAU * lcn[ci[i]]);
            }
        } else {
            for (int it = 0; it < NIT4; ++it) {
                const int j4 = it * 64 + lane;
                if (j4 < C4) {
                    float4 f = ((const float4*)lrow)[j4];
                    float4 l = ((const float4*)lcn)[j4];
                    if (f.x >= thresh) sm += __expf(f.x + TAU * l.x);
                    if (f.y >= thresh) sm += __expf(f.y + TAU * l.y);
                    if (f.z >= thresh) sm += __expf(f.z + TAU * l.z);
                    if (f.w >= thresh) sm += __expf(f.w + TAU * l.w);
                }
            }
        }
    } else {
        // exact re-sweep with max subtraction (never hot)
        z = 0.f;
        for (int it = 0; it < NIT4; ++it) {
            const int j4 = it * 64 + lane;
            if (j4 < C4) {
                float4 f = ((const float4*)lrow)[j4];
                float4 l = ((const float4*)lcn)[j4];
                float e;
                e = __expf(f.x + TAU * l.x - madj); z += e; if (f.x >= thresh) sm += e;
                e = __expf(f.y + TAU * l.y - madj); z += e; if (f.y >= thresh) sm += e;
                e = __expf(f.z + TAU * l.z - madj); z += e; if (f.z >= thresh) sm += e;
                e = __expf(f.w + TAU * l.w - madj); z += e; if (f.w >= thresh) sm += e;
            }
        }
    }

    // ---- Joint wave reduction of z, sm (no LDS, no barrier)
    #pragma unroll
    for (int off = 32; off; off >>= 1) {
        z  += __shfl_down(z, off);
        sm += __shfl_down(sm, off);
    }
    if (lane == 0) {
        const float Z = z, S = sm;
        const float logit_t = lrow[t];
        const float adj_t = logit_t + TAU * lcn[t];
        const float sub = rare ? madj : 0.f;
        const float lpt = adj_t - sub - __logf(Z);             // log_p_adj[target]
        const float p_num = ((logit_t >= thresh) ? __expf(lpt) : 0.f) + 1e-6f;
        const float Smask = S / Z + (float)C_DIM * 1e-6f;
        const float loss = 0.5f * (-lpt + __logf(Smask) - __logf(p_num));
        atomicAdd(out, loss / (float)B);
    }
}

extern "C" void kernel_launch(void* const* d_in, const int* in_sizes, int n_in,
                              void* d_out, int out_size, void* d_ws, size_t ws_size,
                              hipStream_t stream) {
    const float* logit  = (const float*)d_in[0];
    const int*   target = (const int*)d_in[1];
    const float* lcn    = (const float*)d_in[2];
    const int*   kpc    = (const int*)d_in[3];
    float* out = (float*)d_out;
    const int B = in_sizes[1];   // target is [B]

    zero_out_kernel<<<1, 64, 0, stream>>>(out, out_size);
    const int nblk = (B + WPB - 1) / WPB;
    topk_la_loss_kernel<<<nblk, BLOCK, 0, stream>>>(logit, target, lcn, kpc, out, B);
}

// Round 3
// 262.017 us; speedup vs baseline: 1.0943x; 1.0943x over previous
//
#include <hip/hip_runtime.h>

#define BLOCK 256
#define WPB 4                    // waves per block; each owns a quarter-row
#define C_DIM 10000
#define C4 (C_DIM / 4)           // 2500 float4s per row
#define SEGQ (C4 / WPB)          // 625 float4s per wave
#define ITQ ((SEGQ + 63) / 64)   // 10 iterations per wave
#define NIT4 ((C4 + 63) / 64)    // 40 (full-row fallback only)
#define TAU 1.0f
#define CAP 512                  // per-wave candidate cap (mean ~57 at PIV_HI)
#define PIV_HI 2.0f
#define PIV_LO 1.0f

// Monotone bijection float -> uint32 (larger float => larger key)
__device__ __forceinline__ unsigned flip_key(float f) {
    unsigned u = __float_as_uint(f);
    return (u & 0x80000000u) ? ~u : (u | 0x80000000u);
}
__device__ __forceinline__ float unflip_key(unsigned k) {
    unsigned u = (k & 0x80000000u) ? (k & 0x7fffffffu) : ~k;
    return __uint_as_float(u);
}
// # of set bits in m strictly below my lane (64-lane)
__device__ __forceinline__ int mbcnt64(unsigned long long m) {
    return (int)__builtin_amdgcn_mbcnt_hi((unsigned)(m >> 32),
               __builtin_amdgcn_mbcnt_lo((unsigned)(m & 0xffffffffu), 0u));
}

__global__ void zero_out_kernel(float* out, int n) {
    int i = blockIdx.x * blockDim.x + threadIdx.x;
    if (i < n) out[i] = 0.f;
}

// Wave-uniform radix bin pick: each lane owns 4 bins (hv), suffix-scan across
// the wave, exactly one lane picks; result broadcast via shuffles. No barrier.
__device__ __forceinline__ void wave_pick(uint4 hv, int lane, int shift,
                                          unsigned& prefix, unsigned& kr, unsigned& cnt) {
    unsigned loc = hv.x + hv.y + hv.z + hv.w;
    unsigned suf = loc;
    #pragma unroll
    for (int off = 1; off < 64; off <<= 1) {
        unsigned o = (unsigned)__shfl_down((int)suf, off);
        if (lane + off < 64) suf += o;
    }
    unsigned sufex = suf - loc;              // candidates in bins strictly above my 4
    unsigned s3 = sufex + hv.w;
    unsigned s2 = s3 + hv.z;
    unsigned s1 = s2 + hv.y;
    unsigned s0 = s1 + hv.x;
    int bsel = -1; unsigned nkr = 0u, ncnt = 0u;
    if      (s3 >= kr && s3 - hv.w < kr) { bsel = 4 * lane + 3; nkr = kr - (s3 - hv.w); ncnt = hv.w; }
    else if (s2 >= kr && s2 - hv.z < kr) { bsel = 4 * lane + 2; nkr = kr - (s2 - hv.z); ncnt = hv.z; }
    else if (s1 >= kr && s1 - hv.y < kr) { bsel = 4 * lane + 1; nkr = kr - (s1 - hv.y); ncnt = hv.y; }
    else if (s0 >= kr && s0 - hv.x < kr) { bsel = 4 * lane + 0; nkr = kr - (s0 - hv.x); ncnt = hv.x; }
    unsigned long long pm = __ballot(bsel >= 0);
    int src = __ffsll((unsigned long long)pm) - 1;   // exactly one lane picked
    prefix |= ((unsigned)__shfl(bsel, src)) << shift;
    kr  = (unsigned)__shfl((int)nkr, src);
    cnt = (unsigned)__shfl((int)ncnt, src);
}

// Block per row; 4 waves each sweep a contiguous quarter into a private LDS
// segment (ballot compaction, no atomics). 3 barriers total on the hot path.
__global__ __launch_bounds__(BLOCK, 8) void topk_la_loss_kernel(
    const float* __restrict__ logit, const int* __restrict__ target,
    const float* __restrict__ lcn, const int* __restrict__ kpc,
    float* __restrict__ out, int B) {
    __shared__ unsigned candk[WPB][CAP];         // per-wave private segments
    __shared__ unsigned short candi[WPB][CAP];
    __shared__ unsigned hist[256];               // wave 0 only
    __shared__ unsigned sh_nb[WPB];
    __shared__ float red_a[WPB], red_b[WPB];
    __shared__ float sh_thresh;

    const int tid = threadIdx.x;
    const int lane = tid & 63;
    const int wid = tid >> 6;
    const int row = blockIdx.x;
    const float* lrow = logit + (size_t)row * C_DIM;

    const int t = target[row];                   // uniform (broadcast) loads
    int k = kpc[t]; if (k > C_DIM) k = C_DIM;

    unsigned* ck = candk[wid];
    unsigned short* ci = candi[wid];
    const int base4 = wid * SEGQ;                // this wave's quarter (float4 units)

    // ---- Fused sweep over own quarter: z += exp(adj) (|madj|>80 guard handles
    //      overflow), running max(adj), ballot-compact logit >= PIV_HI.
    float z = 0.f, madj = -__builtin_inff();
    unsigned nb = 0u;
    #pragma unroll 2
    for (int it = 0; it < ITQ; ++it) {
        const int j4l = it * 64 + lane;
        float4 f, l;
        if (j4l < SEGQ) {
            f = ((const float4*)lrow)[base4 + j4l];
            l = ((const float4*)lcn)[base4 + j4l];
        } else {                                 // uniform trip count for ballots
            f = make_float4(-1e30f, -1e30f, -1e30f, -1e30f);
            l = make_float4(0.f, 0.f, 0.f, 0.f);
        }
        const float a0 = f.x + TAU * l.x, a1 = f.y + TAU * l.y;
        const float a2 = f.z + TAU * l.z, a3 = f.w + TAU * l.w;
        z += __expf(a0) + __expf(a1) + __expf(a2) + __expf(a3);   // exp(-1e30)=0
        madj = fmaxf(madj, fmaxf(fmaxf(a0, a1), fmaxf(a2, a3)));
        const int j = 4 * (base4 + j4l);
        unsigned long long m;
        m = __ballot(f.x >= PIV_HI);
        if (f.x >= PIV_HI) { unsigned p = nb + (unsigned)mbcnt64(m); if (p < CAP) { ck[p] = __float_as_uint(f.x); ci[p] = (unsigned short)(j + 0); } }
        nb += (unsigned)__popcll(m);
        m = __ballot(f.y >= PIV_HI);
        if (f.y >= PIV_HI) { unsigned p = nb + (unsigned)mbcnt64(m); if (p < CAP) { ck[p] = __float_as_uint(f.y); ci[p] = (unsigned short)(j + 1); } }
        nb += (unsigned)__popcll(m);
        m = __ballot(f.z >= PIV_HI);
        if (f.z >= PIV_HI) { unsigned p = nb + (unsigned)mbcnt64(m); if (p < CAP) { ck[p] = __float_as_uint(f.z); ci[p] = (unsigned short)(j + 2); } }
        nb += (unsigned)__popcll(m);
        m = __ballot(f.w >= PIV_HI);
        if (f.w >= PIV_HI) { unsigned p = nb + (unsigned)mbcnt64(m); if (p < CAP) { ck[p] = __float_as_uint(f.w); ci[p] = (unsigned short)(j + 3); } }
        nb += (unsigned)__popcll(m);
    }
    #pragma unroll
    for (int off = 32; off; off >>= 1) madj = fmaxf(madj, __shfl_xor(madj, off));
    if (lane == 0) { red_a[wid] = madj; sh_nb[wid] = nb; }
    __syncthreads();                             // ---- B1

    const float madjB = fmaxf(fmaxf(red_a[0], red_a[1]), fmaxf(red_a[2], red_a[3]));
    unsigned nbs0 = sh_nb[0], nbs1 = sh_nb[1], nbs2 = sh_nb[2], nbs3 = sh_nb[3];
    unsigned ntot = nbs0 + nbs1 + nbs2 + nbs3;
    unsigned nmax = max(max(nbs0, nbs1), max(nbs2, nbs3));
    int path = (ntot >= (unsigned)k && nmax <= CAP) ? 0 : ((ntot < (unsigned)k) ? 1 : 2);

    // ---- Rare: too few candidates at PIV_HI -> recompact own quarter at PIV_LO
    if (path == 1) {
        nb = 0u;
        for (int it = 0; it < ITQ; ++it) {
            const int j4l = it * 64 + lane;
            float4 f;
            if (j4l < SEGQ) f = ((const float4*)lrow)[base4 + j4l];
            else f = make_float4(-1e30f, -1e30f, -1e30f, -1e30f);
            const int j = 4 * (base4 + j4l);
            unsigned long long m;
            m = __ballot(f.x >= PIV_LO);
            if (f.x >= PIV_LO) { unsigned p = nb + (unsigned)mbcnt64(m); if (p < CAP) { ck[p] = __float_as_uint(f.x); ci[p] = (unsigned short)(j + 0); } }
            nb += (unsigned)__popcll(m);
            m = __ballot(f.y >= PIV_LO);
            if (f.y >= PIV_LO) { unsigned p = nb + (unsigned)mbcnt64(m); if (p < CAP) { ck[p] = __float_as_uint(f.y); ci[p] = (unsigned short)(j + 1); } }
            nb += (unsigned)__popcll(m);
            m = __ballot(f.z >= PIV_LO);
            if (f.z >= PIV_LO) { unsigned p = nb + (unsigned)mbcnt64(m); if (p < CAP) { ck[p] = __float_as_uint(f.z); ci[p] = (unsigned short)(j + 2); } }
            nb += (unsigned)__popcll(m);
            m = __ballot(f.w >= PIV_LO);
            if (f.w >= PIV_LO) { unsigned p = nb + (unsigned)mbcnt64(m); if (p < CAP) { ck[p] = __float_as_uint(f.w); ci[p] = (unsigned short)(j + 3); } }
            nb += (unsigned)__popcll(m);
        }
        if (lane == 0) sh_nb[wid] = nb;
        __syncthreads();                         // B1a (cold path only)
        nbs0 = sh_nb[0]; nbs1 = sh_nb[1]; nbs2 = sh_nb[2]; nbs3 = sh_nb[3];
        ntot = nbs0 + nbs1 + nbs2 + nbs3;
        nmax = max(max(nbs0, nbs1), max(nbs2, nbs3));
        path = (ntot >= (unsigned)k && nmax <= CAP) ? 0 : 2;
    }

    // ---- Select: wave 0 alone, fully wave-synchronous (no barriers inside)
    if (path == 0) {
        if (wid == 0) {
            // Exact byte-radix select among ntot candidates across 4 segments
            // (all >= PIV > 0 -> raw float bits order like uints).
            unsigned prefix = 0u, kr = (unsigned)k, cnt = ntot, kmask = 0u;
            const unsigned nbs[4] = {nbs0, nbs1, nbs2, nbs3};
            for (int q = 0; q < 4; ++q) {
                if (cnt == 1u) break;            // wave-uniform
                const int shift = 24 - 8 * q;
                *(uint4*)&hist[4 * lane] = make_uint4(0u, 0u, 0u, 0u);
                #pragma unroll
                for (int s = 0; s < 4; ++s) {
                    for (int i = lane; i < (int)nbs[s]; i += 64) {
                        unsigned kk = candk[s][i];
                        if ((kk & kmask) == prefix) atomicAdd(&hist[(kk >> shift) & 0xFFu], 1u);
                    }
                }
                uint4 hv = *(const uint4*)&hist[4 * lane];
                wave_pick(hv, lane, shift, prefix, kr, cnt);
                kmask |= (0xFFu << shift);
            }
            if (cnt == 1u && kmask != 0xFFFFFFFFu) {   // unique survivor: full bits
                unsigned found = 0u;
                #pragma unroll
                for (int s = 0; s < 4; ++s) {
                    for (int i = lane; i < (int)nbs[s]; i += 64) {
                        unsigned kk = candk[s][i];
                        if ((kk & kmask) == prefix) found = kk;
                    }
                }
                #pragma unroll
                for (int off = 32; off; off >>= 1) found |= (unsigned)__shfl_xor((int)found, off);
                prefix = found;
            }
            if (lane == 0) sh_thresh = __uint_as_float(prefix);
        }
    } else {
        // Generic fallback (never hot): wave 0 full-row radix on flipped keys
        if (wid == 0) {
            unsigned prefix = 0u, kr = (unsigned)k, cnt = 0u;
            for (int p = 0; p < 4; ++p) {
                const int shift = 24 - 8 * p;
                const unsigned pmask = p ? (0xFFFFFFFFu << (shift + 8)) : 0u;
                *(uint4*)&hist[4 * lane] = make_uint4(0u, 0u, 0u, 0u);
                for (int it = 0; it < NIT4; ++it) {
                    const int j4 = it * 64 + lane;
                    if (j4 < C4) {
                        float4 f = ((const float4*)lrow)[j4];
                        unsigned kk;
                        kk = flip_key(f.x); if ((kk & pmask) == prefix) atomicAdd(&hist[(kk >> shift) & 0xFFu], 1u);
                        kk = flip_key(f.y); if ((kk & pmask) == prefix) atomicAdd(&hist[(kk >> shift) & 0xFFu], 1u);
                        kk = flip_key(f.z); if ((kk & pmask) == prefix) atomicAdd(&hist[(kk >> shift) & 0xFFu], 1u);
                        kk = flip_key(f.w); if ((kk & pmask) == prefix) atomicAdd(&hist[(kk >> shift) & 0xFFu], 1u);
                    }
                }
                uint4 hv = *(const uint4*)&hist[4 * lane];
                wave_pick(hv, lane, shift, prefix, kr, cnt);
            }
            if (lane == 0) sh_thresh = unflip_key(prefix);
        }
    }
    __syncthreads();                             // ---- B2
    const float thresh = sh_thresh;

    const bool rare = fabsf(madjB) > 80.f;       // exp(adj) over/underflow guard
    float sm = 0.f;
    if (!rare) {
        if (path == 0) {
            // masked set is a subset of this wave's own candidates
            const int nc = (int)sh_nb[wid];
            for (int i = lane; i < nc; i += 64) {
                const float v = __uint_as_float(ck[i]);
                if (v >= thresh) sm += __expf(v + TAU * lcn[ci[i]]);
            }
        } else {
            for (int it = 0; it < ITQ; ++it) {
                const int j4l = it * 64 + lane;
                if (j4l < SEGQ) {
                    float4 f = ((const float4*)lrow)[base4 + j4l];
                    float4 l = ((const float4*)lcn)[base4 + j4l];
                    if (f.x >= thresh) sm += __expf(f.x + TAU * l.x);
                    if (f.y >= thresh) sm += __expf(f.y + TAU * l.y);
                    if (f.z >= thresh) sm += __expf(f.z + TAU * l.z);
                    if (f.w >= thresh) sm += __expf(f.w + TAU * l.w);
                }
            }
        }
    } else {
        // exact re-sweep of own quarter with max subtraction (never hot)
        z = 0.f;
        for (int it = 0; it < ITQ; ++it) {
            const int j4l = it * 64 + lane;
            if (j4l < SEGQ) {
                float4 f = ((const float4*)lrow)[base4 + j4l];
                float4 l = ((const float4*)lcn)[base4 + j4l];
                float e;
                e = __expf(f.x + TAU * l.x - madjB); z += e; if (f.x >= thresh) sm += e;
                e = __expf(f.y + TAU * l.y - madjB); z += e; if (f.y >= thresh) sm += e;
                e = __expf(f.z + TAU * l.z - madjB); z += e; if (f.z >= thresh) sm += e;
                e = __expf(f.w + TAU * l.w - madjB); z += e; if (f.w >= thresh) sm += e;
            }
        }
    }

    // ---- Joint reduction of z, sm: wave-level shuffles, then 4 values via LDS
    #pragma unroll
    for (int off = 32; off; off >>= 1) {
        z  += __shfl_down(z, off);
        sm += __shfl_down(sm, off);
    }
    if (lane == 0) { red_a[wid] = z; red_b[wid] = sm; }
    __syncthreads();                             // ---- B3

    if (tid == 0) {
        const float Z = red_a[0] + red_a[1] + red_a[2] + red_a[3];
        const float S = red_b[0] + red_b[1] + red_b[2] + red_b[3];
        const float logit_t = lrow[t];
        const float adj_t = logit_t + TAU * lcn[t];
        const float sub = rare ? madjB : 0.f;
        const float lpt = adj_t - sub - __logf(Z);             // log_p_adj[target]
        const float p_num = ((logit_t >= thresh) ? __expf(lpt) : 0.f) + 1e-6f;
        const float Smask = S / Z + (float)C_DIM * 1e-6f;
        const float loss = 0.5f * (-lpt + __logf(Smask) - __logf(p_num));
        atomicAdd(out, loss / (float)B);
    }
}

extern "C" void kernel_launch(void* const* d_in, const int* in_sizes, int n_in,
                              void* d_out, int out_size, void* d_ws, size_t ws_size,
                              hipStream_t stream) {
    const float* logit  = (const float*)d_in[0];
    const int*   target = (const int*)d_in[1];
    const float* lcn    = (const float*)d_in[2];
    const int*   kpc    = (const int*)d_in[3];
    float* out = (float*)d_out;
    const int B = in_sizes[1];   // target is [B]

    zero_out_kernel<<<1, 64, 0, stream>>>(out, out_size);
    topk_la_loss_kernel<<<B, BLOCK, 0, stream>>>(logit, target, lcn, kpc, out, B);
}

// Round 4
// 241.300 us; speedup vs baseline: 1.1883x; 1.0859x over previous
//
#include <hip/hip_runtime.h>

#define BLOCK 256
#define WPB 4                    // waves per block; each owns a quarter-row
#define C_DIM 10000
#define C4 (C_DIM / 4)           // 2500 float4s per row
#define SEGQ (C4 / WPB)          // 625 float4s per wave
#define ITQ ((SEGQ + 63) / 64)   // 10 register-prefetched iterations per wave
#define NIT4 ((C4 + 63) / 64)    // 40 (full-row fallback only)
#define TAU 1.0f
#define CAP 512                  // per-wave candidate cap (mean ~57 at PIV_HI)
#define PIV_HI 2.0f
#define PIV_LO 1.0f

// Monotone bijection float -> uint32 (larger float => larger key)
__device__ __forceinline__ unsigned flip_key(float f) {
    unsigned u = __float_as_uint(f);
    return (u & 0x80000000u) ? ~u : (u | 0x80000000u);
}
__device__ __forceinline__ float unflip_key(unsigned k) {
    unsigned u = (k & 0x80000000u) ? (k & 0x7fffffffu) : ~k;
    return __uint_as_float(u);
}
// # of set bits in m strictly below my lane (64-lane)
__device__ __forceinline__ int mbcnt64(unsigned long long m) {
    return (int)__builtin_amdgcn_mbcnt_hi((unsigned)(m >> 32),
               __builtin_amdgcn_mbcnt_lo((unsigned)(m & 0xffffffffu), 0u));
}

__global__ void zero_out_kernel(float* out, int n) {
    int i = blockIdx.x * blockDim.x + threadIdx.x;
    if (i < n) out[i] = 0.f;
}

// Wave-uniform radix bin pick: each lane owns 4 bins (hv), suffix-scan across
// the wave, exactly one lane picks; result broadcast via shuffles. No barrier.
__device__ __forceinline__ void wave_pick(uint4 hv, int lane, int shift,
                                          unsigned& prefix, unsigned& kr, unsigned& cnt) {
    unsigned loc = hv.x + hv.y + hv.z + hv.w;
    unsigned suf = loc;
    #pragma unroll
    for (int off = 1; off < 64; off <<= 1) {
        unsigned o = (unsigned)__shfl_down((int)suf, off);
        if (lane + off < 64) suf += o;
    }
    unsigned sufex = suf - loc;              // candidates in bins strictly above my 4
    unsigned s3 = sufex + hv.w;
    unsigned s2 = s3 + hv.z;
    unsigned s1 = s2 + hv.y;
    unsigned s0 = s1 + hv.x;
    int bsel = -1; unsigned nkr = 0u, ncnt = 0u;
    if      (s3 >= kr && s3 - hv.w < kr) { bsel = 4 * lane + 3; nkr = kr - (s3 - hv.w); ncnt = hv.w; }
    else if (s2 >= kr && s2 - hv.z < kr) { bsel = 4 * lane + 2; nkr = kr - (s2 - hv.z); ncnt = hv.z; }
    else if (s1 >= kr && s1 - hv.y < kr) { bsel = 4 * lane + 1; nkr = kr - (s1 - hv.y); ncnt = hv.y; }
    else if (s0 >= kr && s0 - hv.x < kr) { bsel = 4 * lane + 0; nkr = kr - (s0 - hv.x); ncnt = hv.x; }
    unsigned long long pm = __ballot(bsel >= 0);
    int src = __ffsll((unsigned long long)pm) - 1;   // exactly one lane picked
    prefix |= ((unsigned)__shfl(bsel, src)) << shift;
    kr  = (unsigned)__shfl((int)nkr, src);
    cnt = (unsigned)__shfl((int)ncnt, src);
}

// Block per row; 4 waves each prefetch their contiguous quarter-row entirely
// into registers (20 float4 loads in flight), then compute + ballot-compact.
// 3 barriers total on the hot path.
__global__ __launch_bounds__(BLOCK, 4) void topk_la_loss_kernel(
    const float* __restrict__ logit, const int* __restrict__ target,
    const float* __restrict__ lcn, const int* __restrict__ kpc,
    float* __restrict__ out, int B) {
    __shared__ unsigned candk[WPB][CAP];         // per-wave private segments
    __shared__ unsigned short candi[WPB][CAP];
    __shared__ unsigned hist[256];               // wave 0 only
    __shared__ unsigned sh_nb[WPB];
    __shared__ float red_a[WPB], red_b[WPB];
    __shared__ float sh_thresh;

    const int tid = threadIdx.x;
    const int lane = tid & 63;
    const int wid = tid >> 6;
    const int row = blockIdx.x;
    const float* lrow = logit + (size_t)row * C_DIM;

    const int t = target[row];                   // uniform (broadcast) loads
    int k = kpc[t]; if (k > C_DIM) k = C_DIM;
    const float logit_t = lrow[t];               // hoisted: hides tail latency
    const float lcn_t = lcn[t];

    unsigned* ck = candk[wid];
    unsigned short* ci = candi[wid];
    const int base4 = wid * SEGQ;                // this wave's quarter (float4 units)

    // ---- Register prefetch: issue ALL 20 loads back-to-back (MLP ~20KB/wave).
    float4 fv[ITQ], lv[ITQ];
    #pragma unroll
    for (int it = 0; it < ITQ; ++it) {
        const int j4l = it * 64 + lane;
        if (j4l < SEGQ) {                        // always true for it<9
            fv[it] = ((const float4*)lrow)[base4 + j4l];
            lv[it] = ((const float4*)lcn)[base4 + j4l];
        } else {
            fv[it] = make_float4(-1e30f, -1e30f, -1e30f, -1e30f);
            lv[it] = make_float4(0.f, 0.f, 0.f, 0.f);
        }
    }

    // ---- Fused compute over registers: z += exp(adj) (|madj|>80 guard handles
    //      overflow), running max(adj), ballot-compact logit >= PIV_HI.
    float z0 = 0.f, z1 = 0.f, z2 = 0.f, z3 = 0.f;
    float mA = -__builtin_inff(), mB = -__builtin_inff();
    unsigned nb = 0u;
    #pragma unroll
    for (int it = 0; it < ITQ; ++it) {
        const float4 f = fv[it], l = lv[it];
        const float a0 = f.x + TAU * l.x, a1 = f.y + TAU * l.y;
        const float a2 = f.z + TAU * l.z, a3 = f.w + TAU * l.w;
        z0 += __expf(a0); z1 += __expf(a1);      // exp(-1e30)=0 for pad lanes
        z2 += __expf(a2); z3 += __expf(a3);
        mA = fmaxf(mA, fmaxf(a0, a1));
        mB = fmaxf(mB, fmaxf(a2, a3));
        const int j = 4 * (base4 + it * 64 + lane);
        unsigned long long m;
        m = __ballot(f.x >= PIV_HI);
        if (f.x >= PIV_HI) { unsigned p = nb + (unsigned)mbcnt64(m); if (p < CAP) { ck[p] = __float_as_uint(f.x); ci[p] = (unsigned short)(j + 0); } }
        nb += (unsigned)__popcll(m);
        m = __ballot(f.y >= PIV_HI);
        if (f.y >= PIV_HI) { unsigned p = nb + (unsigned)mbcnt64(m); if (p < CAP) { ck[p] = __float_as_uint(f.y); ci[p] = (unsigned short)(j + 1); } }
        nb += (unsigned)__popcll(m);
        m = __ballot(f.z >= PIV_HI);
        if (f.z >= PIV_HI) { unsigned p = nb + (unsigned)mbcnt64(m); if (p < CAP) { ck[p] = __float_as_uint(f.z); ci[p] = (unsigned short)(j + 2); } }
        nb += (unsigned)__popcll(m);
        m = __ballot(f.w >= PIV_HI);
        if (f.w >= PIV_HI) { unsigned p = nb + (unsigned)mbcnt64(m); if (p < CAP) { ck[p] = __float_as_uint(f.w); ci[p] = (unsigned short)(j + 3); } }
        nb += (unsigned)__popcll(m);
    }
    float z = (z0 + z1) + (z2 + z3);
    float madj = fmaxf(mA, mB);
    #pragma unroll
    for (int off = 32; off; off >>= 1) madj = fmaxf(madj, __shfl_xor(madj, off));
    if (lane == 0) { red_a[wid] = madj; sh_nb[wid] = nb; }
    __syncthreads();                             // ---- B1

    const float madjB = fmaxf(fmaxf(red_a[0], red_a[1]), fmaxf(red_a[2], red_a[3]));
    unsigned nbs0 = sh_nb[0], nbs1 = sh_nb[1], nbs2 = sh_nb[2], nbs3 = sh_nb[3];
    unsigned ntot = nbs0 + nbs1 + nbs2 + nbs3;
    unsigned nmax = max(max(nbs0, nbs1), max(nbs2, nbs3));
    int path = (ntot >= (unsigned)k && nmax <= CAP) ? 0 : ((ntot < (unsigned)k) ? 1 : 2);

    // ---- Rare: too few candidates at PIV_HI -> recompact own quarter at PIV_LO
    if (path == 1) {
        nb = 0u;
        for (int it = 0; it < ITQ; ++it) {
            const int j4l = it * 64 + lane;
            float4 f;
            if (j4l < SEGQ) f = ((const float4*)lrow)[base4 + j4l];
            else f = make_float4(-1e30f, -1e30f, -1e30f, -1e30f);
            const int j = 4 * (base4 + j4l);
            unsigned long long m;
            m = __ballot(f.x >= PIV_LO);
            if (f.x >= PIV_LO) { unsigned p = nb + (unsigned)mbcnt64(m); if (p < CAP) { ck[p] = __float_as_uint(f.x); ci[p] = (unsigned short)(j + 0); } }
            nb += (unsigned)__popcll(m);
            m = __ballot(f.y >= PIV_LO);
            if (f.y >= PIV_LO) { unsigned p = nb + (unsigned)mbcnt64(m); if (p < CAP) { ck[p] = __float_as_uint(f.y); ci[p] = (unsigned short)(j + 1); } }
            nb += (unsigned)__popcll(m);
            m = __ballot(f.z >= PIV_LO);
            if (f.z >= PIV_LO) { unsigned p = nb + (unsigned)mbcnt64(m); if (p < CAP) { ck[p] = __float_as_uint(f.z); ci[p] = (unsigned short)(j + 2); } }
            nb += (unsigned)__popcll(m);
            m = __ballot(f.w >= PIV_LO);
            if (f.w >= PIV_LO) { unsigned p = nb + (unsigned)mbcnt64(m); if (p < CAP) { ck[p] = __float_as_uint(f.w); ci[p] = (unsigned short)(j + 3); } }
            nb += (unsigned)__popcll(m);
        }
        if (lane == 0) sh_nb[wid] = nb;
        __syncthreads();                         // B1a (cold path only)
        nbs0 = sh_nb[0]; nbs1 = sh_nb[1]; nbs2 = sh_nb[2]; nbs3 = sh_nb[3];
        ntot = nbs0 + nbs1 + nbs2 + nbs3;
        nmax = max(max(nbs0, nbs1), max(nbs2, nbs3));
        path = (ntot >= (unsigned)k && nmax <= CAP) ? 0 : 2;
    }

    // ---- Select: wave 0 alone, fully wave-synchronous (no barriers inside)
    if (path == 0) {
        if (wid == 0) {
            // Exact byte-radix select among ntot candidates across 4 segments
            // (all >= PIV > 0 -> raw float bits order like uints).
            unsigned prefix = 0u, kr = (unsigned)k, cnt = ntot, kmask = 0u;
            const unsigned nbs[4] = {nbs0, nbs1, nbs2, nbs3};
            for (int q = 0; q < 4; ++q) {
                if (cnt == 1u) break;            // wave-uniform
                const int shift = 24 - 8 * q;
                *(uint4*)&hist[4 * lane] = make_uint4(0u, 0u, 0u, 0u);
                #pragma unroll
                for (int s = 0; s < 4; ++s) {
                    for (int i = lane; i < (int)nbs[s]; i += 64) {
                        unsigned kk = candk[s][i];
                        if ((kk & kmask) == prefix) atomicAdd(&hist[(kk >> shift) & 0xFFu], 1u);
                    }
                }
                uint4 hv = *(const uint4*)&hist[4 * lane];
                wave_pick(hv, lane, shift, prefix, kr, cnt);
                kmask |= (0xFFu << shift);
            }
            if (cnt == 1u && kmask != 0xFFFFFFFFu) {   // unique survivor: full bits
                unsigned found = 0u;
                #pragma unroll
                for (int s = 0; s < 4; ++s) {
                    for (int i = lane; i < (int)nbs[s]; i += 64) {
                        unsigned kk = candk[s][i];
                        if ((kk & kmask) == prefix) found = kk;
                    }
                }
                #pragma unroll
                for (int off = 32; off; off >>= 1) found |= (unsigned)__shfl_xor((int)found, off);
                prefix = found;
            }
            if (lane == 0) sh_thresh = __uint_as_float(prefix);
        }
    } else {
        // Generic fallback (never hot): wave 0 full-row radix on flipped keys
        if (wid == 0) {
            unsigned prefix = 0u, kr = (unsigned)k, cnt = 0u;
            for (int p = 0; p < 4; ++p) {
                const int shift = 24 - 8 * p;
                const unsigned pmask = p ? (0xFFFFFFFFu << (shift + 8)) : 0u;
                *(uint4*)&hist[4 * lane] = make_uint4(0u, 0u, 0u, 0u);
                for (int it = 0; it < NIT4; ++it) {
                    const int j4 = it * 64 + lane;
                    if (j4 < C4) {
                        float4 f = ((const float4*)lrow)[j4];
                        unsigned kk;
                        kk = flip_key(f.x); if ((kk & pmask) == prefix) atomicAdd(&hist[(kk >> shift) & 0xFFu], 1u);
                        kk = flip_key(f.y); if ((kk & pmask) == prefix) atomicAdd(&hist[(kk >> shift) & 0xFFu], 1u);
                        kk = flip_key(f.z); if ((kk & pmask) == prefix) atomicAdd(&hist[(kk >> shift) & 0xFFu], 1u);
                        kk = flip_key(f.w); if ((kk & pmask) == prefix) atomicAdd(&hist[(kk >> shift) & 0xFFu], 1u);
                    }
                }
                uint4 hv = *(const uint4*)&hist[4 * lane];
                wave_pick(hv, lane, shift, prefix, kr, cnt);
            }
            if (lane == 0) sh_thresh = unflip_key(prefix);
        }
    }
    __syncthreads();                             // ---- B2
    const float thresh = sh_thresh;

    const bool rare = fabsf(madjB) > 80.f;       // exp(adj) over/underflow guard
    float sm = 0.f;
    if (!rare) {
        if (path == 0) {
            // masked set is a subset of this wave's own candidates
            const int nc = (int)sh_nb[wid];
            for (int i = lane; i < nc; i += 64) {
                const float v = __uint_as_float(ck[i]);
                if (v >= thresh) sm += __expf(v + TAU * lcn[ci[i]]);
            }
        } else {
            for (int it = 0; it < ITQ; ++it) {
                const int j4l = it * 64 + lane;
                if (j4l < SEGQ) {
                    float4 f = ((const float4*)lrow)[base4 + j4l];
                    float4 l = ((const float4*)lcn)[base4 + j4l];
                    if (f.x >= thresh) sm += __expf(f.x + TAU * l.x);
                    if (f.y >= thresh) sm += __expf(f.y + TAU * l.y);
                    if (f.z >= thresh) sm += __expf(f.z + TAU * l.z);
                    if (f.w >= thresh) sm += __expf(f.w + TAU * l.w);
                }
            }
        }
    } else {
        // exact re-sweep of own quarter with max subtraction (never hot)
        z = 0.f;
        for (int it = 0; it < ITQ; ++it) {
            const int j4l = it * 64 + lane;
            if (j4l < SEGQ) {
                float4 f = ((const float4*)lrow)[base4 + j4l];
                float4 l = ((const float4*)lcn)[base4 + j4l];
                float e;
                e = __expf(f.x + TAU * l.x - madjB); z += e; if (f.x >= thresh) sm += e;
                e = __expf(f.y + TAU * l.y - madjB); z += e; if (f.y >= thresh) sm += e;
                e = __expf(f.z + TAU * l.z - madjB); z += e; if (f.z >= thresh) sm += e;
                e = __expf(f.w + TAU * l.w - madjB); z += e; if (f.w >= thresh) sm += e;
            }
        }
    }

    // ---- Joint reduction of z, sm: wave-level shuffles, then 4 values via LDS
    #pragma unroll
    for (int off = 32; off; off >>= 1) {
        z  += __shfl_down(z, off);
        sm += __shfl_down(sm, off);
    }
    if (lane == 0) { red_a[wid] = z; red_b[wid] = sm; }
    __syncthreads();                             // ---- B3

    if (tid == 0) {
        const float Z = red_a[0] + red_a[1] + red_a[2] + red_a[3];
        const float S = red_b[0] + red_b[1] + red_b[2] + red_b[3];
        const float adj_t = logit_t + TAU * lcn_t;
        const float sub = rare ? madjB : 0.f;
        const float lpt = adj_t - sub - __logf(Z);             // log_p_adj[target]
        const float p_num = ((logit_t >= thresh) ? __expf(lpt) : 0.f) + 1e-6f;
        const float Smask = S / Z + (float)C_DIM * 1e-6f;
        const float loss = 0.5f * (-lpt + __logf(Smask) - __logf(p_num));
        atomicAdd(out, loss / (float)B);
    }
}

extern "C" void kernel_launch(void* const* d_in, const int* in_sizes, int n_in,
                              void* d_out, int out_size, void* d_ws, size_t ws_size,
                              hipStream_t stream) {
    const float* logit  = (const float*)d_in[0];
    const int*   target = (const int*)d_in[1];
    const float* lcn    = (const float*)d_in[2];
    const int*   kpc    = (const int*)d_in[3];
    float* out = (float*)d_out;
    const int B = in_sizes[1];   // target is [B]

    zero_out_kernel<<<1, 64, 0, stream>>>(out, out_size);
    topk_la_loss_kernel<<<B, BLOCK, 0, stream>>>(logit, target, lcn, kpc, out, B);
}